// Round 1
// baseline (279.782 us; speedup 1.0000x reference)
//
#include <hip/hip_runtime.h>

typedef _Float16 v8h __attribute__((ext_vector_type(8)));
typedef float v16f __attribute__((ext_vector_type(16)));

// ---------------------------------------------------------------------------
// Prep: BT[o][k_outer*IN + i] = (k_outer<64) ? w2[k_outer, i*64+o] : b2[i*64+o]
// stored f16, row-major [64, K], K = 65*IN
// ---------------------------------------------------------------------------
__global__ void prep_bt(const float* __restrict__ w2, const float* __restrict__ b2,
                        _Float16* __restrict__ BT, int IN, int Ktot, int total) {
    int idx = blockIdx.x * 256 + threadIdx.x;
    if (idx >= total) return;
    int o = idx / Ktot, kk = idx - o * Ktot;
    int ko = kk / IN, i = kk - ko * IN;
    float v = (ko < 64) ? w2[ko * (IN * 64) + i * 64 + o] : b2[i * 64 + o];
    BT[idx] = (_Float16)v;
}

// relu1_ext [E, 66] f16: cols 0..63 = relu(ea@w1 + b1), col 64 = 1.0, col 65 pad
__global__ void prep_r1(const float* __restrict__ ea, const float* __restrict__ w1,
                        const float* __restrict__ b1, _Float16* __restrict__ r1, int E) {
    int idx = blockIdx.x * 256 + threadIdx.x;
    if (idx >= E * 66) return;
    int e = idx / 66, j = idx - e * 66;
    float v;
    if (j < 64)       v = fmaxf(ea[e * 2] * w1[j] + ea[e * 2 + 1] * w1[64 + j] + b1[j], 0.f);
    else if (j == 64) v = 1.f;
    else              v = 0.f;
    r1[idx] = (_Float16)v;
}

__global__ void cvt_f16(const float* __restrict__ s, _Float16* __restrict__ d, int n) {
    int idx = blockIdx.x * 256 + threadIdx.x;
    if (idx < n) d[idx] = (_Float16)s[idx];
}

// agg[n,o] = bias[o] + sum_i x[n,i]*root[i,o]   (fp32, x fp32)
__global__ void node_root(const float* __restrict__ x, const float* __restrict__ root,
                          const float* __restrict__ bias, float* __restrict__ agg,
                          int N, int IN) {
    int idx = blockIdx.x * 256 + threadIdx.x;
    if (idx >= N * 64) return;
    int n = idx >> 6, o = idx & 63;
    float s = bias[o];
    const float* xr = x + (size_t)n * IN;
    for (int i = 0; i < IN; ++i) s += xr[i] * root[i * 64 + o];
    agg[idx] = s;
}

// x1b[n,o] = f16(relu(agg0[n,o]));  agg1[n,o] = bias1[o] + sum_i relu(agg0[n,i])*root1[i,o]
__global__ void mid_kernel(const float* __restrict__ agg0, const float* __restrict__ root1,
                           const float* __restrict__ bias1, _Float16* __restrict__ x1b,
                           float* __restrict__ agg1, int N) {
    int idx = blockIdx.x * 256 + threadIdx.x;
    if (idx >= N * 64) return;
    int n = idx >> 6, o = idx & 63;
    const float* ar = agg0 + (size_t)n * 64;
    float s = bias1[o];
    #pragma unroll 8
    for (int i = 0; i < 64; ++i) s += fmaxf(ar[i], 0.f) * root1[i * 64 + o];
    agg1[idx] = s;
    x1b[idx] = (_Float16)fmaxf(agg0[idx], 0.f);
}

__global__ void final_relu(const float* __restrict__ agg1, float* __restrict__ out, int n) {
    int idx = blockIdx.x * 256 + threadIdx.x;
    if (idx < n) out[idx] = fmaxf(agg1[idx], 0.f);
}

// ---------------------------------------------------------------------------
// Edge GEMM: msg[e,:] = (relu1_ext[e] (x) x_src[e]) @ BT^T, scatter-add to agg[dst[e]]
// Block: 128 threads = 2 waves; tile = 128 edges x 64 out. Wave tile 64x64 via
// v_mfma_f32_32x32x16_f16 (2 m-frags x 2 n-frags). A generated in registers:
// A[m][ko*IN + i] = relu1[m][ko] * x[m][i]. K-split x2 via blockIdx.y (atomics
// make the split free).
// ---------------------------------------------------------------------------
template<int IN_C>
__global__ __launch_bounds__(128, 2)
void edge_gemm(const _Float16* __restrict__ r1, const _Float16* __restrict__ xb,
               const _Float16* __restrict__ BT, const int* __restrict__ srcI,
               const int* __restrict__ dstI, float* __restrict__ agg, int E) {
    constexpr int KT  = 65 * IN_C;   // total K
    constexpr int PH  = IN_C / 16;   // K-steps (of 16) per k_outer
    constexpr int CPR = IN_C / 8;    // 16B chunks per x row

    __shared__ _Float16 sh_r1[128][66];
    __shared__ _Float16 sh_x[128][IN_C];
    __shared__ int sh_dst[128];

    int tid = threadIdx.x;
    int ebase = blockIdx.x * 128;
    int valid = E - ebase; if (valid > 128) valid = 128;

    sh_dst[tid] = (tid < valid) ? dstI[ebase + tid] : 0;

    // relu1 tile: rows are contiguous 33 dwords each, flat copy
    {
        const unsigned int* g = (const unsigned int*)(r1 + (size_t)ebase * 66);
        unsigned int* s = (unsigned int*)&sh_r1[0][0];
        for (int i = tid; i < valid * 33; i += 128) s[i] = g[i];
    }
    // gathered x tile
    for (int i = tid; i < 128 * CPR; i += 128) {
        int r = i / CPR, c = i - r * CPR;
        int sidx = (r < valid) ? srcI[ebase + r] : 0;
        *(uint4*)&sh_x[r][c * 8] = *(const uint4*)(xb + (size_t)sidx * IN_C + (size_t)c * 8);
    }
    __syncthreads();

    int wv = tid >> 6, lane = tid & 63, ln = lane & 31, g2 = lane >> 5;
    int mr0 = wv * 64 + ln, mr1 = mr0 + 32;

    // x slices held in registers: lane's 8-wide i-slice per phase per m-frag
    v8h xs0[PH], xs1[PH];
    #pragma unroll
    for (int p = 0; p < PH; ++p) {
        xs0[p] = *(const v8h*)&sh_x[mr0][p * 16 + g2 * 8];
        xs1[p] = *(const v8h*)&sh_x[mr1][p * 16 + g2 * 8];
    }

    v16f acc00 = {0,0,0,0,0,0,0,0,0,0,0,0,0,0,0,0};
    v16f acc01 = acc00, acc10 = acc00, acc11 = acc00;

    const _Float16* bp0 = BT + (size_t)ln * KT + g2 * 8;
    const _Float16* bp1 = bp0 + (size_t)32 * KT;

    int kb = (blockIdx.y * 65) >> 1;          // 0 | 32
    int ke = ((blockIdx.y + 1) * 65) >> 1;    // 32 | 65
    #pragma unroll 2
    for (int ko = kb; ko < ke; ++ko) {
        _Float16 sv0 = sh_r1[mr0][ko];
        _Float16 sv1 = sh_r1[mr1][ko];
        #pragma unroll
        for (int p = 0; p < PH; ++p) {
            int kk = ko * IN_C + p * 16;
            v8h b0 = *(const v8h*)(bp0 + kk);
            v8h b1 = *(const v8h*)(bp1 + kk);
            v8h a0 = xs0[p] * sv0;
            v8h a1 = xs1[p] * sv1;
            acc00 = __builtin_amdgcn_mfma_f32_32x32x16_f16(a0, b0, acc00, 0, 0, 0);
            acc01 = __builtin_amdgcn_mfma_f32_32x32x16_f16(a0, b1, acc01, 0, 0, 0);
            acc10 = __builtin_amdgcn_mfma_f32_32x32x16_f16(a1, b0, acc10, 0, 0, 0);
            acc11 = __builtin_amdgcn_mfma_f32_32x32x16_f16(a1, b1, acc11, 0, 0, 0);
        }
    }

    // epilogue: C/D layout (32x32): col = lane&31, row = 4*(lane>>5) + (r&3) + 8*(r>>2)
    auto scatter = [&](const v16f& c, int mf, int nf) {
        int col = nf * 32 + ln;
        #pragma unroll
        for (int r = 0; r < 16; ++r) {
            int row = wv * 64 + mf * 32 + 4 * g2 + (r & 3) + 8 * (r >> 2);
            if (row < valid)
                atomicAdd(&agg[(size_t)sh_dst[row] * 64 + col], c[r]);
        }
    };
    scatter(acc00, 0, 0);
    scatter(acc01, 0, 1);
    scatter(acc10, 1, 0);
    scatter(acc11, 1, 1);
}

// ---------------------------------------------------------------------------
extern "C" void kernel_launch(void* const* d_in, const int* in_sizes, int n_in,
                              void* d_out, int out_size, void* d_ws, size_t ws_size,
                              hipStream_t stream) {
    const float* x      = (const float*)d_in[0];
    const int*   ei     = (const int*)d_in[1];
    const float* ea     = (const float*)d_in[2];
    const float* w1_0   = (const float*)d_in[3];
    const float* b1_0   = (const float*)d_in[4];
    const float* w2_0   = (const float*)d_in[5];
    const float* b2_0   = (const float*)d_in[6];
    const float* root_0 = (const float*)d_in[7];
    const float* bias_0 = (const float*)d_in[8];
    const float* w1_1   = (const float*)d_in[9];
    const float* b1_1   = (const float*)d_in[10];
    const float* w2_1   = (const float*)d_in[11];
    const float* b2_1   = (const float*)d_in[12];
    const float* root_1 = (const float*)d_in[13];
    const float* bias_1 = (const float*)d_in[14];
    float* out = (float*)d_out;

    int N = in_sizes[0] / 32;
    int E = in_sizes[1] / 2;
    const int* srcI = ei;
    const int* dstI = ei + E;

    char* ws = (char*)d_ws;
    size_t off = 0;
    auto carve = [&](size_t bytes) {
        void* p = ws + off;
        off += (bytes + 255) & ~(size_t)255;
        return p;
    };
    _Float16* BT0  = (_Float16*)carve((size_t)64 * 2080 * 2);
    _Float16* BT1  = (_Float16*)carve((size_t)64 * 4160 * 2);
    _Float16* R10  = (_Float16*)carve((size_t)E * 66 * 2);
    _Float16* R11  = (_Float16*)carve((size_t)E * 66 * 2);
    _Float16* XB0  = (_Float16*)carve((size_t)N * 32 * 2);
    _Float16* X1B  = (_Float16*)carve((size_t)N * 64 * 2);
    float*    AGG0 = (float*)carve((size_t)N * 64 * 4);
    float*    AGG1 = (float*)carve((size_t)N * 64 * 4);

    int t0 = 64 * 2080, t1 = 64 * 4160;
    prep_bt<<<(t0 + 255) / 256, 256, 0, stream>>>(w2_0, b2_0, BT0, 32, 2080, t0);
    prep_bt<<<(t1 + 255) / 256, 256, 0, stream>>>(w2_1, b2_1, BT1, 64, 4160, t1);
    prep_r1<<<(E * 66 + 255) / 256, 256, 0, stream>>>(ea, w1_0, b1_0, R10, E);
    prep_r1<<<(E * 66 + 255) / 256, 256, 0, stream>>>(ea, w1_1, b1_1, R11, E);
    cvt_f16<<<(N * 32 + 255) / 256, 256, 0, stream>>>(x, XB0, N * 32);

    node_root<<<(N * 64 + 255) / 256, 256, 0, stream>>>(x, root_0, bias_0, AGG0, N, 32);

    dim3 ggrid((E + 127) / 128, 2);
    edge_gemm<32><<<ggrid, 128, 0, stream>>>(R10, XB0, BT0, srcI, dstI, AGG0, E);

    mid_kernel<<<(N * 64 + 255) / 256, 256, 0, stream>>>(AGG0, root_1, bias_1, X1B, AGG1, N);

    edge_gemm<64><<<ggrid, 128, 0, stream>>>(R11, X1B, BT1, srcI, dstI, AGG1, E);

    final_relu<<<(N * 64 + 255) / 256, 256, 0, stream>>>(AGG1, out, N * 64);
}

// Round 2
// 239.044 us; speedup vs baseline: 1.1704x; 1.1704x over previous
//
#include <hip/hip_runtime.h>

typedef _Float16 v8h __attribute__((ext_vector_type(8)));
typedef float v16f __attribute__((ext_vector_type(16)));

// ---------------------------------------------------------------------------
// BT[o][ko*IN + i] = (ko<64) ? w2[ko, i*64+o] : b2[i*64+o], f16 [64, 65*IN]
// Both layers in one dispatch.
// ---------------------------------------------------------------------------
__global__ void prep_bt_both(const float* __restrict__ w2_0, const float* __restrict__ b2_0,
                             _Float16* __restrict__ BT0,
                             const float* __restrict__ w2_1, const float* __restrict__ b2_1,
                             _Float16* __restrict__ BT1) {
    int idx = blockIdx.x * 256 + threadIdx.x;
    const int t0 = 64 * 2080, t1 = 64 * 4160;
    if (idx < t0) {
        int o = idx / 2080, kk = idx - o * 2080;
        int ko = kk / 32, i = kk - ko * 32;
        float v = (ko < 64) ? w2_0[ko * (32 * 64) + i * 64 + o] : b2_0[i * 64 + o];
        BT0[idx] = (_Float16)v;
    } else if (idx < t0 + t1) {
        int j = idx - t0;
        int o = j / 4160, kk = j - o * 4160;
        int ko = kk / 64, i = kk - ko * 64;
        float v = (ko < 64) ? w2_1[ko * (64 * 64) + i * 64 + o] : b2_1[i * 64 + o];
        BT1[j] = (_Float16)v;
    }
}

// relu1_ext [E, 66] f16 for BOTH layers: cols 0..63 = relu(ea@w1+b1), 64 = 1, 65 = 0
__global__ void prep_r1_both(const float* __restrict__ ea,
                             const float* __restrict__ w1_0, const float* __restrict__ b1_0,
                             const float* __restrict__ w1_1, const float* __restrict__ b1_1,
                             _Float16* __restrict__ r1_0, _Float16* __restrict__ r1_1, int E) {
    int idx = blockIdx.x * 256 + threadIdx.x;
    if (idx >= E * 66) return;
    int e = idx / 66, j = idx - e * 66;
    float v0, v1;
    if (j < 64) {
        float a = ea[e * 2], b = ea[e * 2 + 1];
        v0 = fmaxf(a * w1_0[j] + b * w1_0[64 + j] + b1_0[j], 0.f);
        v1 = fmaxf(a * w1_1[j] + b * w1_1[64 + j] + b1_1[j], 0.f);
    } else if (j == 64) { v0 = 1.f; v1 = 1.f; }
    else               { v0 = 0.f; v1 = 0.f; }
    r1_0[idx] = (_Float16)v0;
    r1_1[idx] = (_Float16)v1;
}

// agg0[n,o] = bias0[o] + sum_i x[n,i]*root0[i,o]; also emits x in f16
__global__ void node_root_cvt(const float* __restrict__ x, const float* __restrict__ root,
                              const float* __restrict__ bias, float* __restrict__ agg,
                              _Float16* __restrict__ xb, int N) {
    int idx = blockIdx.x * 256 + threadIdx.x;
    if (idx >= N * 64) return;
    int n = idx >> 6, o = idx & 63;
    float s = bias[o];
    const float* xr = x + (size_t)n * 32;
    #pragma unroll 8
    for (int i = 0; i < 32; ++i) s += xr[i] * root[i * 64 + o];
    agg[idx] = s;
    if (o < 32) xb[n * 32 + o] = (_Float16)xr[o];
}

// x1b = f16(relu(agg0)); agg1[n,o] = bias1[o] + sum_i relu(agg0[n,i])*root1[i,o]
__global__ void mid_kernel(const float* __restrict__ agg0, const float* __restrict__ root1,
                           const float* __restrict__ bias1, _Float16* __restrict__ x1b,
                           float* __restrict__ agg1, int N) {
    int idx = blockIdx.x * 256 + threadIdx.x;
    if (idx >= N * 64) return;
    int n = idx >> 6, o = idx & 63;
    const float* ar = agg0 + (size_t)n * 64;
    float s = bias1[o];
    #pragma unroll 8
    for (int i = 0; i < 64; ++i) s += fmaxf(ar[i], 0.f) * root1[i * 64 + o];
    agg1[idx] = s;
    x1b[idx] = (_Float16)fmaxf(agg0[idx], 0.f);
}

__global__ void final_relu(const float* __restrict__ agg1, float* __restrict__ out, int n) {
    int idx = blockIdx.x * 256 + threadIdx.x;
    if (idx < n) out[idx] = fmaxf(agg1[idx], 0.f);
}

// ---------------------------------------------------------------------------
// Edge GEMM, v2: 64-edge tile, 256 threads = 4 waves, K-split over the 4 waves
// inside the block (ko quarter each). Each wave computes the full 64x64 tile
// partial via v_mfma_f32_32x32x16_f16 (2 m-frags x 2 n-frags). Partials are
// reduced through 2 LDS fp32 buffers (waves 0/1 store, 2/3 add), then ONE
// atomicAdd per element scatters to agg[dst]. A generated in registers:
// A[m][ko*IN+i] = r1[m][ko] * x[m][i].
// ---------------------------------------------------------------------------
template<int IN_C>
__global__ __launch_bounds__(256, 3)
void edge_gemm(const _Float16* __restrict__ r1, const _Float16* __restrict__ xb,
               const _Float16* __restrict__ BT, const int* __restrict__ srcI,
               const int* __restrict__ dstI, float* __restrict__ agg, int E) {
    constexpr int KT  = 65 * IN_C;   // total K
    constexpr int PH  = IN_C / 16;   // 16-wide K-steps per k_outer
    constexpr int CPR = IN_C / 8;    // 16B chunks per x row

    __shared__ _Float16 sh_r1[64][66];
    __shared__ _Float16 sh_x[64][IN_C];
    __shared__ int sh_dst[64];
    __shared__ float buf[2][64][65];

    int tid = threadIdx.x;
    int ebase = blockIdx.x * 64;
    int valid = E - ebase; if (valid > 64) valid = 64;

    if (tid < 64) sh_dst[tid] = (tid < valid) ? dstI[ebase + tid] : 0;

    {   // relu1 tile: rows contiguous (33 dwords each), flat copy
        const unsigned int* g = (const unsigned int*)(r1 + (size_t)ebase * 66);
        unsigned int* s = (unsigned int*)&sh_r1[0][0];
        for (int i = tid; i < valid * 33; i += 256) s[i] = g[i];
    }
    // gathered x tile
    for (int i = tid; i < 64 * CPR; i += 256) {
        int r = i / CPR, c = i - r * CPR;
        int sidx = (r < valid) ? srcI[ebase + r] : 0;
        *(uint4*)&sh_x[r][c * 8] = *(const uint4*)(xb + (size_t)sidx * IN_C + (size_t)c * 8);
    }
    __syncthreads();

    int wv = tid >> 6, lane = tid & 63, ln = lane & 31, g2 = lane >> 5;
    int mr0 = ln, mr1 = ln + 32;

    // x slices in registers: lane's 8-wide i-slice per phase per m-frag
    v8h xs0[PH], xs1[PH];
    #pragma unroll
    for (int p = 0; p < PH; ++p) {
        xs0[p] = *(const v8h*)&sh_x[mr0][p * 16 + g2 * 8];
        xs1[p] = *(const v8h*)&sh_x[mr1][p * 16 + g2 * 8];
    }

    v16f acc00 = {0,0,0,0,0,0,0,0,0,0,0,0,0,0,0,0};
    v16f acc01 = acc00, acc10 = acc00, acc11 = acc00;

    const _Float16* bp0 = BT + (size_t)ln * KT + g2 * 8;
    const _Float16* bp1 = bp0 + (size_t)32 * KT;

    int kb = (wv * 65) >> 2, ke = ((wv + 1) * 65) >> 2;  // per-wave K quarter
    #pragma unroll 2
    for (int ko = kb; ko < ke; ++ko) {
        _Float16 sv0 = sh_r1[mr0][ko];
        _Float16 sv1 = sh_r1[mr1][ko];
        v8h b0[PH], b1[PH];
        #pragma unroll
        for (int p = 0; p < PH; ++p) {   // batch B loads: PH*2 in flight
            int kk = ko * IN_C + p * 16;
            b0[p] = *(const v8h*)(bp0 + kk);
            b1[p] = *(const v8h*)(bp1 + kk);
        }
        #pragma unroll
        for (int p = 0; p < PH; ++p) {
            v8h a0 = xs0[p] * sv0;
            v8h a1 = xs1[p] * sv1;
            acc00 = __builtin_amdgcn_mfma_f32_32x32x16_f16(a0, b0[p], acc00, 0, 0, 0);
            acc01 = __builtin_amdgcn_mfma_f32_32x32x16_f16(a0, b1[p], acc01, 0, 0, 0);
            acc10 = __builtin_amdgcn_mfma_f32_32x32x16_f16(a1, b0[p], acc10, 0, 0, 0);
            acc11 = __builtin_amdgcn_mfma_f32_32x32x16_f16(a1, b1[p], acc11, 0, 0, 0);
        }
    }

    // cross-wave reduce: waves 0/1 store into buf[wv&1], waves 2/3 add
    float (*mybuf)[65] = buf[wv & 1];
    auto emit = [&](const v16f& c, int mf, int nf, bool add) {
        int col = nf * 32 + ln;
        #pragma unroll
        for (int r = 0; r < 16; ++r) {
            int row = mf * 32 + 4 * g2 + (r & 3) + 8 * (r >> 2);
            if (add) mybuf[row][col] += c[r];
            else     mybuf[row][col]  = c[r];
        }
    };
    if (wv < 2) {
        emit(acc00, 0, 0, false); emit(acc01, 0, 1, false);
        emit(acc10, 1, 0, false); emit(acc11, 1, 1, false);
    }
    __syncthreads();
    if (wv >= 2) {
        emit(acc00, 0, 0, true); emit(acc01, 0, 1, true);
        emit(acc10, 1, 0, true); emit(acc11, 1, 1, true);
    }
    __syncthreads();

    // single atomic per output element
    for (int t = tid; t < 64 * 64; t += 256) {
        int row = t >> 6, col = t & 63;
        if (row < valid)
            atomicAdd(&agg[(size_t)sh_dst[row] * 64 + col],
                      buf[0][row][col] + buf[1][row][col]);
    }
}

// ---------------------------------------------------------------------------
extern "C" void kernel_launch(void* const* d_in, const int* in_sizes, int n_in,
                              void* d_out, int out_size, void* d_ws, size_t ws_size,
                              hipStream_t stream) {
    const float* x      = (const float*)d_in[0];
    const int*   ei     = (const int*)d_in[1];
    const float* ea     = (const float*)d_in[2];
    const float* w1_0   = (const float*)d_in[3];
    const float* b1_0   = (const float*)d_in[4];
    const float* w2_0   = (const float*)d_in[5];
    const float* b2_0   = (const float*)d_in[6];
    const float* root_0 = (const float*)d_in[7];
    const float* bias_0 = (const float*)d_in[8];
    const float* w1_1   = (const float*)d_in[9];
    const float* b1_1   = (const float*)d_in[10];
    const float* w2_1   = (const float*)d_in[11];
    const float* b2_1   = (const float*)d_in[12];
    const float* root_1 = (const float*)d_in[13];
    const float* bias_1 = (const float*)d_in[14];
    float* out = (float*)d_out;

    int N = in_sizes[0] / 32;
    int E = in_sizes[1] / 2;
    const int* srcI = ei;
    const int* dstI = ei + E;

    char* ws = (char*)d_ws;
    size_t off = 0;
    auto carve = [&](size_t bytes) {
        void* p = ws + off;
        off += (bytes + 255) & ~(size_t)255;
        return p;
    };
    _Float16* BT0  = (_Float16*)carve((size_t)64 * 2080 * 2);
    _Float16* BT1  = (_Float16*)carve((size_t)64 * 4160 * 2);
    _Float16* R10  = (_Float16*)carve((size_t)E * 66 * 2);
    _Float16* R11  = (_Float16*)carve((size_t)E * 66 * 2);
    _Float16* XB0  = (_Float16*)carve((size_t)N * 32 * 2);
    _Float16* X1B  = (_Float16*)carve((size_t)N * 64 * 2);
    float*    AGG0 = (float*)carve((size_t)N * 64 * 4);
    float*    AGG1 = (float*)carve((size_t)N * 64 * 4);

    int tbt = 64 * 2080 + 64 * 4160;
    prep_bt_both<<<(tbt + 255) / 256, 256, 0, stream>>>(w2_0, b2_0, BT0, w2_1, b2_1, BT1);
    prep_r1_both<<<(E * 66 + 255) / 256, 256, 0, stream>>>(ea, w1_0, b1_0, w1_1, b1_1, R10, R11, E);
    node_root_cvt<<<(N * 64 + 255) / 256, 256, 0, stream>>>(x, root_0, bias_0, AGG0, XB0, N);

    int gblocks = (E + 63) / 64;
    edge_gemm<32><<<gblocks, 256, 0, stream>>>(R10, XB0, BT0, srcI, dstI, AGG0, E);

    mid_kernel<<<(N * 64 + 255) / 256, 256, 0, stream>>>(AGG0, root_1, bias_1, X1B, AGG1, N);

    edge_gemm<64><<<gblocks, 256, 0, stream>>>(R11, X1B, BT1, srcI, dstI, AGG1, E);

    final_relu<<<(N * 64 + 255) / 256, 256, 0, stream>>>(AGG1, out, N * 64);
}